// Round 17
// baseline (286.315 us; speedup 1.0000x reference)
//
#include <hip/hip_runtime.h>

#define F 128
#define RPB 64          // rows per bucket
#define MAXNB 1792      // LDS bucket-histogram capacity (>= nbk = 1563)
#define CHUNK 8192      // edges per rank-scatter/histo block
#define EPT 32          // edges per thread (CHUNK/256)
#define CAP 3072        // LDS edge capacity per sort/spmm batch (> max bucket size)
#define SPMM_T 512      // threads in fused sort+spmm block (8 waves)
#define HELD (CAP/SPMM_T)
#define PERSIST 1024    // persistent spmm grid: 32-wave/CU cap at 512 threads

// ---------------- fallback: atomic COO (round-4 proven) ----------------
__global__ void spmm_coo_atomic(const int* __restrict__ rows,
                                const int* __restrict__ cols,
                                const float* __restrict__ vals,
                                const float* __restrict__ x,
                                float* __restrict__ out,
                                int nnz, int n_rows) {
    int t = blockIdx.x * blockDim.x + threadIdx.x;
    int e = t >> 5;
    int g = t & 31;
    if (e >= nnz) return;
    int r = rows[e];
    int c = cols[e];
    float v = vals[e];
    if ((unsigned)r >= (unsigned)n_rows || (unsigned)c >= (unsigned)n_rows) return;
    const float4 xv = *reinterpret_cast<const float4*>(x + (size_t)c * F + g * 4);
    float* o = out + (size_t)r * F + g * 4;
    atomicAdd(o + 0, v * xv.x);
    atomicAdd(o + 1, v * xv.y);
    atomicAdd(o + 2, v * xv.z);
    atomicAdd(o + 3, v * xv.w);
}

// ---------------- K0: fused x->bf16 convert + bucket histogram ----------------
__device__ __forceinline__ unsigned f2bf(float f) {
    unsigned u = __float_as_uint(f);
    return (u + 0x7FFFu + ((u >> 16) & 1u)) >> 16;   // round-to-nearest-even
}

__global__ void k_cvt_histo(const float* __restrict__ x, unsigned short* __restrict__ xb,
                            long long xtotal,
                            const int* __restrict__ rows, int* __restrict__ cnt,
                            int nnz, int nbk, int n, int cvtb) {
    __shared__ int lc[MAXNB];
    if ((int)blockIdx.x < cvtb) {
        long long i = ((long long)blockIdx.x * 256 + threadIdx.x) * 8;
        if (i >= xtotal) return;
        float4 a = *reinterpret_cast<const float4*>(x + i);
        float4 b = *reinterpret_cast<const float4*>(x + i + 4);
        uint4 o;
        o.x = f2bf(a.x) | (f2bf(a.y) << 16);
        o.y = f2bf(a.z) | (f2bf(a.w) << 16);
        o.z = f2bf(b.x) | (f2bf(b.y) << 16);
        o.w = f2bf(b.z) | (f2bf(b.w) << 16);
        *reinterpret_cast<uint4*>(xb + i) = o;
    } else {
        for (int i = threadIdx.x; i < nbk; i += 256) lc[i] = 0;
        __syncthreads();
        int base = ((int)blockIdx.x - cvtb) * CHUNK;
#pragma unroll
        for (int k = 0; k < EPT; ++k) {
            int e = base + k * 256 + threadIdx.x;
            if (e < nnz) {
                int r = rows[e];
                if ((unsigned)r < (unsigned)n) atomicAdd(&lc[r / RPB], 1);
            }
        }
        __syncthreads();
        for (int i = threadIdx.x; i < nbk; i += 256) {
            int c = lc[i];
            if (c) atomicAdd(&cnt[i], c);
        }
    }
}

// ---------------- K2: single-block exclusive scan over buckets ----------------
__global__ void k_bucket_scan(const int* __restrict__ cnt, int* __restrict__ off,
                              int* __restrict__ gcur, int nbk) {
    __shared__ int s[256];
    int tid = threadIdx.x;
    int per = (nbk + 255) / 256;      // <= 7
    int base = tid * per;
    int loc[8];
    int tsum = 0;
#pragma unroll
    for (int k = 0; k < 8; ++k) {
        int i = base + k;
        int v = (k < per && i < nbk) ? cnt[i] : 0;
        loc[k] = v;
        tsum += v;
    }
    s[tid] = tsum;
    __syncthreads();
    for (int o = 1; o < 256; o <<= 1) {
        int t = (tid >= o) ? s[tid - o] : 0;
        __syncthreads();
        s[tid] += t;
        __syncthreads();
    }
    int run = s[tid] - tsum;
#pragma unroll
    for (int k = 0; k < 8; ++k) {
        int i = base + k;
        if (k < per && i < nbk) { off[i] = run; gcur[i] = run; }
        run += loc[k];
    }
    if (tid == 255) off[nbk] = s[255];
}

// ---------------- K3: ranked bucket scatter (coalesced runs, NT stores) -------
__global__ void k_rank_scatter(const int* __restrict__ rows, const int* __restrict__ cols,
                               const float* __restrict__ vals, int* __restrict__ gcur,
                               int2* __restrict__ pair, int nnz, int nbk, int n) {
    __shared__ int lcnt[MAXNB];
    __shared__ int lbase[MAXNB];
    for (int i = threadIdx.x; i < nbk; i += 256) lcnt[i] = 0;
    __syncthreads();
    int base = blockIdx.x * CHUNK;
    unsigned br[EPT];                 // packed (b << 19) | (lr << 13) | rank
#pragma unroll
    for (int k = 0; k < EPT; ++k) {
        int e = base + k * 256 + threadIdx.x;
        br[k] = 0xFFFFFFFFu;
        if (e < nnz) {
            int r = rows[e];
            if ((unsigned)r < (unsigned)n) {
                int b = r / RPB;
                int lr = r - b * RPB;
                int rk = atomicAdd(&lcnt[b], 1);
                br[k] = ((unsigned)b << 19) | ((unsigned)lr << 13) | (unsigned)rk;
            }
        }
    }
    __syncthreads();
    for (int i = threadIdx.x; i < nbk; i += 256) {
        int c = lcnt[i];
        if (c) lbase[i] = atomicAdd(&gcur[i], c);
    }
    __syncthreads();
#pragma unroll
    for (int k = 0; k < EPT; ++k) {
        if (br[k] != 0xFFFFFFFFu) {
            int e = base + k * 256 + threadIdx.x;
            int b = br[k] >> 19;
            int lr = (br[k] >> 13) & 63;
            int rk = br[k] & 0x1FFF;
            int c = cols[e];
            if ((unsigned)c >= (unsigned)n) c = 0;
            int pos = lbase[b] + rk;
            unsigned long long pv = (unsigned)((lr << 17) | c)
                                  | ((unsigned long long)(unsigned)__float_as_int(vals[e]) << 32);
            __builtin_nontemporal_store(pv, (unsigned long long*)&pair[pos]);
        }
    }
}

// ---------------- K4: persistent fused within-bucket sort + SpMM --------------
// NT pair loads + NT out stores keep L2 dedicated to the xb gather set.
__global__ void __launch_bounds__(SPMM_T) k_sort_spmm(const int* __restrict__ off,
                                                      const int2* __restrict__ pair,
                                                      const unsigned short* __restrict__ xb,
                                                      float* __restrict__ out,
                                                      int n, int nbk) {
    __shared__ int2 eb[CAP];
    __shared__ int rcnt[RPB];
    __shared__ int rst[RPB + 1];
    __shared__ int rcur[RPB];

    int tid = threadIdx.x;
    int wave = tid >> 6;        // 0..7
    int lane = tid & 63;
    int q = lane >> 4;          // quarter 0..3 (edge slot)
    int fl = lane & 15;         // feature lane: owns 8 bf16 (16B)

    for (int b = blockIdx.x; b < nbk; b += gridDim.x) {
        int beg = off[b], end = off[b + 1];
        bool first = true;
        int bb = beg;
        do {
            int bn = min(CAP, end - bb);   // may be 0 for an empty bucket
            if (tid < RPB) rcnt[tid] = 0;
            __syncthreads();

            int2 held[HELD];
#pragma unroll
            for (int k = 0; k < HELD; ++k) {
                int j = tid + k * SPMM_T;
                held[k] = make_int2(0, 0);
                if (j < bn) {
                    unsigned long long pv = __builtin_nontemporal_load(
                        (const unsigned long long*)&pair[bb + j]);
                    int2 pr = make_int2((int)(unsigned)(pv & 0xFFFFFFFFull),
                                        (int)(unsigned)(pv >> 32));
                    held[k] = pr;
                    atomicAdd(&rcnt[pr.x >> 17], 1);
                }
            }
            __syncthreads();

            if (tid < RPB) {
                int v = rcnt[tid];
                int sc = v;
                for (int o = 1; o < RPB; o <<= 1) {
                    int t = __shfl_up(sc, o);
                    if (tid >= o) sc += t;
                }
                rst[tid + 1] = sc;
                if (tid == 0) rst[0] = 0;
                rcur[tid] = sc - v;
            }
            __syncthreads();

#pragma unroll
            for (int k = 0; k < HELD; ++k) {
                int j = tid + k * SPMM_T;
                if (j < bn) {
                    int2 pr = held[k];
                    int lr = pr.x >> 17;
                    int pos = atomicAdd(&rcur[lr], 1);
                    eb[pos] = make_int2(pr.x & 0x1FFFF, pr.y);
                }
            }
            __syncthreads();

            for (int rr = 0; rr < 8; ++rr) {
                int lr = wave * 8 + rr;
                int s0 = rst[lr], s1 = rst[lr + 1];
                float acc[8] = {0.f, 0.f, 0.f, 0.f, 0.f, 0.f, 0.f, 0.f};
#pragma unroll 2
                for (int j = s0 + q; j < s1; j += 4) {
                    int2 e = eb[j];
                    int col = e.x;
                    float vk = __int_as_float(e.y);
                    uint4 w = *reinterpret_cast<const uint4*>(xb + (size_t)col * F + fl * 8);
                    acc[0] += vk * __uint_as_float(w.x << 16);
                    acc[1] += vk * __uint_as_float(w.x & 0xFFFF0000u);
                    acc[2] += vk * __uint_as_float(w.y << 16);
                    acc[3] += vk * __uint_as_float(w.y & 0xFFFF0000u);
                    acc[4] += vk * __uint_as_float(w.z << 16);
                    acc[5] += vk * __uint_as_float(w.z & 0xFFFF0000u);
                    acc[6] += vk * __uint_as_float(w.w << 16);
                    acc[7] += vk * __uint_as_float(w.w & 0xFFFF0000u);
                }
#pragma unroll
                for (int i = 0; i < 8; ++i) {
                    acc[i] += __shfl_xor(acc[i], 16);
                    acc[i] += __shfl_xor(acc[i], 32);
                }
                if (q == 0) {
                    long long row = (long long)b * RPB + lr;
                    if (row < n) {
                        float* po = out + (size_t)row * F + fl * 8;
                        if (first) {
                            union { float2 f; unsigned long long u; } c0, c1, c2, c3;
                            c0.f = make_float2(acc[0], acc[1]);
                            c1.f = make_float2(acc[2], acc[3]);
                            c2.f = make_float2(acc[4], acc[5]);
                            c3.f = make_float2(acc[6], acc[7]);
                            __builtin_nontemporal_store(c0.u, (unsigned long long*)(po));
                            __builtin_nontemporal_store(c1.u, (unsigned long long*)(po + 2));
                            __builtin_nontemporal_store(c2.u, (unsigned long long*)(po + 4));
                            __builtin_nontemporal_store(c3.u, (unsigned long long*)(po + 6));
                        } else {
                            float4 t0 = *reinterpret_cast<const float4*>(po);
                            float4 t1 = *reinterpret_cast<const float4*>(po + 4);
                            t0.x += acc[0]; t0.y += acc[1]; t0.z += acc[2]; t0.w += acc[3];
                            t1.x += acc[4]; t1.y += acc[5]; t1.z += acc[6]; t1.w += acc[7];
                            *reinterpret_cast<float4*>(po) = t0;
                            *reinterpret_cast<float4*>(po + 4) = t1;
                        }
                    }
                }
            }
            first = false;
            bb += CAP;
            __syncthreads();
        } while (bb < end);
    }
}

extern "C" void kernel_launch(void* const* d_in, const int* in_sizes, int n_in,
                              void* d_out, int out_size, void* d_ws, size_t ws_size,
                              hipStream_t stream) {
    const float* x = (const float*)d_in[0];
    const int* A_ind = (const int*)d_in[1];
    const float* A_val = (const float*)d_in[2];
    float* out = (float*)d_out;

    const int nnz = in_sizes[2];
    const int n = out_size / F;              // 100000
    const int nbk = (n + RPB - 1) / RPB;     // 1563 buckets
    const int* rows = A_ind;
    const int* cols = A_ind + nnz;

    const long long xtotal = (long long)n * F;

    const size_t need = (size_t)nnz * 8              // pair
                      + (size_t)xtotal * 2           // x bf16
                      + (size_t)(3 * nbk + 1) * 4 + 128;

    if (nbk > MAXNB || (xtotal % 8) != 0 || ws_size < need) {
        hipMemsetAsync(d_out, 0, (size_t)out_size * sizeof(float), stream);
        const long long total = (long long)nnz * 32;
        spmm_coo_atomic<<<(int)((total + 255) / 256), 256, 0, stream>>>(
            rows, cols, A_val, x, out, nnz, n);
        return;
    }

    char* w = (char*)d_ws;
    int2* pair = (int2*)w;            w += (size_t)nnz * 8;
    unsigned short* xb = (unsigned short*)w;  w += (size_t)xtotal * 2;
    int* cnt = (int*)w;               w += (size_t)nbk * 4;
    int* off = (int*)w;               w += (size_t)(nbk + 1) * 4;
    int* gcur = (int*)w;

    const int nchunks = (nnz + CHUNK - 1) / CHUNK;
    const int cvtb = (int)((xtotal / 8 + 255) / 256);

    hipMemsetAsync(cnt, 0, (size_t)nbk * 4, stream);
    k_cvt_histo<<<cvtb + nchunks, 256, 0, stream>>>(x, xb, xtotal, rows, cnt,
                                                    nnz, nbk, n, cvtb);
    k_bucket_scan<<<1, 256, 0, stream>>>(cnt, off, gcur, nbk);
    k_rank_scatter<<<nchunks, 256, 0, stream>>>(rows, cols, A_val, gcur, pair,
                                                nnz, nbk, n);
    // Writes every output row exactly once (zeros for empty rows) -> no out memset.
    const int pgrid = (nbk < PERSIST) ? nbk : PERSIST;
    k_sort_spmm<<<pgrid, SPMM_T, 0, stream>>>(off, pair, xb, out, n, nbk);
}

// Round 18
// 211.619 us; speedup vs baseline: 1.3530x; 1.3530x over previous
//
#include <hip/hip_runtime.h>

#define F 128
#define RPB 64          // rows per bucket
#define MAXNB 1792      // LDS bucket-histogram capacity (>= nbk = 1563)
#define CHUNK 8192      // edges per rank-scatter/histo block
#define EPT 32          // edges per thread in histo (CHUNK/256)
#define SEPT 16         // edges per thread in rank_scatter (CHUNK/512)
#define CAP 3072        // LDS edge capacity per sort/spmm batch (> max bucket size)
#define SPMM_T 512      // threads in fused sort+spmm block (8 waves)
#define HELD (CAP/SPMM_T)
#define PERSIST 1024    // persistent spmm grid: 32-wave/CU cap at 512 threads

// ---------------- fallback: atomic COO (round-4 proven) ----------------
__global__ void spmm_coo_atomic(const int* __restrict__ rows,
                                const int* __restrict__ cols,
                                const float* __restrict__ vals,
                                const float* __restrict__ x,
                                float* __restrict__ out,
                                int nnz, int n_rows) {
    int t = blockIdx.x * blockDim.x + threadIdx.x;
    int e = t >> 5;
    int g = t & 31;
    if (e >= nnz) return;
    int r = rows[e];
    int c = cols[e];
    float v = vals[e];
    if ((unsigned)r >= (unsigned)n_rows || (unsigned)c >= (unsigned)n_rows) return;
    const float4 xv = *reinterpret_cast<const float4*>(x + (size_t)c * F + g * 4);
    float* o = out + (size_t)r * F + g * 4;
    atomicAdd(o + 0, v * xv.x);
    atomicAdd(o + 1, v * xv.y);
    atomicAdd(o + 2, v * xv.z);
    atomicAdd(o + 3, v * xv.w);
}

// ---------------- K0: fused x->bf16 convert + bucket histogram ----------------
__device__ __forceinline__ unsigned f2bf(float f) {
    unsigned u = __float_as_uint(f);
    return (u + 0x7FFFu + ((u >> 16) & 1u)) >> 16;   // round-to-nearest-even
}

__global__ void k_cvt_histo(const float* __restrict__ x, unsigned short* __restrict__ xb,
                            long long xtotal,
                            const int* __restrict__ rows, int* __restrict__ cnt,
                            int nnz, int nbk, int n, int cvtb) {
    __shared__ int lc[MAXNB];
    if ((int)blockIdx.x < cvtb) {
        long long i = ((long long)blockIdx.x * 256 + threadIdx.x) * 8;
        if (i >= xtotal) return;
        float4 a = *reinterpret_cast<const float4*>(x + i);
        float4 b = *reinterpret_cast<const float4*>(x + i + 4);
        uint4 o;
        o.x = f2bf(a.x) | (f2bf(a.y) << 16);
        o.y = f2bf(a.z) | (f2bf(a.w) << 16);
        o.z = f2bf(b.x) | (f2bf(b.y) << 16);
        o.w = f2bf(b.z) | (f2bf(b.w) << 16);
        *reinterpret_cast<uint4*>(xb + i) = o;
    } else {
        for (int i = threadIdx.x; i < nbk; i += 256) lc[i] = 0;
        __syncthreads();
        int base = ((int)blockIdx.x - cvtb) * CHUNK;
#pragma unroll
        for (int k = 0; k < EPT; ++k) {
            int e = base + k * 256 + threadIdx.x;
            if (e < nnz) {
                int r = rows[e];
                if ((unsigned)r < (unsigned)n) atomicAdd(&lc[r / RPB], 1);
            }
        }
        __syncthreads();
        for (int i = threadIdx.x; i < nbk; i += 256) {
            int c = lc[i];
            if (c) atomicAdd(&cnt[i], c);
        }
    }
}

// ---------------- K2: single-block exclusive scan over buckets ----------------
__global__ void k_bucket_scan(const int* __restrict__ cnt, int* __restrict__ off,
                              int* __restrict__ gcur, int nbk) {
    __shared__ int s[256];
    int tid = threadIdx.x;
    int per = (nbk + 255) / 256;      // <= 7
    int base = tid * per;
    int loc[8];
    int tsum = 0;
#pragma unroll
    for (int k = 0; k < 8; ++k) {
        int i = base + k;
        int v = (k < per && i < nbk) ? cnt[i] : 0;
        loc[k] = v;
        tsum += v;
    }
    s[tid] = tsum;
    __syncthreads();
    for (int o = 1; o < 256; o <<= 1) {
        int t = (tid >= o) ? s[tid - o] : 0;
        __syncthreads();
        s[tid] += t;
        __syncthreads();
    }
    int run = s[tid] - tsum;
#pragma unroll
    for (int k = 0; k < 8; ++k) {
        int i = base + k;
        if (k < per && i < nbk) { off[i] = run; gcur[i] = run; }
        run += loc[k];
    }
    if (tid == 255) off[nbk] = s[255];
}

// ---------------- K3: ranked bucket scatter (coalesced runs, 8 waves) ---------
__global__ void __launch_bounds__(512) k_rank_scatter(
        const int* __restrict__ rows, const int* __restrict__ cols,
        const float* __restrict__ vals, int* __restrict__ gcur,
        int2* __restrict__ pair, int nnz, int nbk, int n) {
    __shared__ int lcnt[MAXNB];
    __shared__ int lbase[MAXNB];
    int tid = threadIdx.x;
    for (int i = tid; i < nbk; i += 512) lcnt[i] = 0;
    __syncthreads();
    int base = blockIdx.x * CHUNK;
    unsigned br[SEPT];                // packed (b << 19) | (lr << 13) | rank
#pragma unroll
    for (int k = 0; k < SEPT; ++k) {
        int e = base + k * 512 + tid;
        br[k] = 0xFFFFFFFFu;
        if (e < nnz) {
            int r = rows[e];
            if ((unsigned)r < (unsigned)n) {
                int b = r / RPB;
                int lr = r - b * RPB;
                int rk = atomicAdd(&lcnt[b], 1);
                br[k] = ((unsigned)b << 19) | ((unsigned)lr << 13) | (unsigned)rk;
            }
        }
    }
    __syncthreads();
    for (int i = tid; i < nbk; i += 512) {
        int c = lcnt[i];
        if (c) lbase[i] = atomicAdd(&gcur[i], c);
    }
    __syncthreads();
#pragma unroll
    for (int k = 0; k < SEPT; ++k) {
        if (br[k] != 0xFFFFFFFFu) {
            int e = base + k * 512 + tid;
            int b = br[k] >> 19;
            int lr = (br[k] >> 13) & 63;
            int rk = br[k] & 0x1FFF;
            int c = cols[e];
            if ((unsigned)c >= (unsigned)n) c = 0;
            int pos = lbase[b] + rk;
            pair[pos] = make_int2((lr << 17) | c, __float_as_int(vals[e]));
        }
    }
}

// ---------------- K4: persistent fused within-bucket sort + SpMM --------------
__global__ void __launch_bounds__(SPMM_T) k_sort_spmm(const int* __restrict__ off,
                                                      const int2* __restrict__ pair,
                                                      const unsigned short* __restrict__ xb,
                                                      float* __restrict__ out,
                                                      int n, int nbk) {
    __shared__ int2 eb[CAP];
    __shared__ int rcnt[RPB];
    __shared__ int rst[RPB + 1];
    __shared__ int rcur[RPB];

    int tid = threadIdx.x;
    int wave = tid >> 6;        // 0..7
    int lane = tid & 63;
    int q = lane >> 4;          // quarter 0..3 (edge slot)
    int fl = lane & 15;         // feature lane: owns 8 bf16 (16B)

    for (int b = blockIdx.x; b < nbk; b += gridDim.x) {
        int beg = off[b], end = off[b + 1];
        bool first = true;
        int bb = beg;
        do {
            int bn = min(CAP, end - bb);   // may be 0 for an empty bucket
            if (tid < RPB) rcnt[tid] = 0;
            __syncthreads();

            int2 held[HELD];
#pragma unroll
            for (int k = 0; k < HELD; ++k) {
                int j = tid + k * SPMM_T;
                held[k] = make_int2(0, 0);
                if (j < bn) {
                    int2 pr = pair[bb + j];
                    held[k] = pr;
                    atomicAdd(&rcnt[pr.x >> 17], 1);
                }
            }
            __syncthreads();

            if (tid < RPB) {
                int v = rcnt[tid];
                int sc = v;
                for (int o = 1; o < RPB; o <<= 1) {
                    int t = __shfl_up(sc, o);
                    if (tid >= o) sc += t;
                }
                rst[tid + 1] = sc;
                if (tid == 0) rst[0] = 0;
                rcur[tid] = sc - v;
            }
            __syncthreads();

#pragma unroll
            for (int k = 0; k < HELD; ++k) {
                int j = tid + k * SPMM_T;
                if (j < bn) {
                    int2 pr = held[k];
                    int lr = pr.x >> 17;
                    int pos = atomicAdd(&rcur[lr], 1);
                    eb[pos] = make_int2(pr.x & 0x1FFFF, pr.y);
                }
            }
            __syncthreads();

            for (int rr = 0; rr < 8; ++rr) {
                int lr = wave * 8 + rr;
                int s0 = rst[lr], s1 = rst[lr + 1];
                float acc[8] = {0.f, 0.f, 0.f, 0.f, 0.f, 0.f, 0.f, 0.f};
#pragma unroll 2
                for (int j = s0 + q; j < s1; j += 4) {
                    int2 e = eb[j];
                    int col = e.x;
                    float vk = __int_as_float(e.y);
                    uint4 w = *reinterpret_cast<const uint4*>(xb + (size_t)col * F + fl * 8);
                    acc[0] += vk * __uint_as_float(w.x << 16);
                    acc[1] += vk * __uint_as_float(w.x & 0xFFFF0000u);
                    acc[2] += vk * __uint_as_float(w.y << 16);
                    acc[3] += vk * __uint_as_float(w.y & 0xFFFF0000u);
                    acc[4] += vk * __uint_as_float(w.z << 16);
                    acc[5] += vk * __uint_as_float(w.z & 0xFFFF0000u);
                    acc[6] += vk * __uint_as_float(w.w << 16);
                    acc[7] += vk * __uint_as_float(w.w & 0xFFFF0000u);
                }
#pragma unroll
                for (int i = 0; i < 8; ++i) {
                    acc[i] += __shfl_xor(acc[i], 16);
                    acc[i] += __shfl_xor(acc[i], 32);
                }
                if (q == 0) {
                    long long row = (long long)b * RPB + lr;
                    if (row < n) {
                        float* po = out + (size_t)row * F + fl * 8;
                        float4 lo = make_float4(acc[0], acc[1], acc[2], acc[3]);
                        float4 hi = make_float4(acc[4], acc[5], acc[6], acc[7]);
                        if (first) {
                            *reinterpret_cast<float4*>(po) = lo;
                            *reinterpret_cast<float4*>(po + 4) = hi;
                        } else {
                            float4 t0 = *reinterpret_cast<const float4*>(po);
                            float4 t1 = *reinterpret_cast<const float4*>(po + 4);
                            t0.x += lo.x; t0.y += lo.y; t0.z += lo.z; t0.w += lo.w;
                            t1.x += hi.x; t1.y += hi.y; t1.z += hi.z; t1.w += hi.w;
                            *reinterpret_cast<float4*>(po) = t0;
                            *reinterpret_cast<float4*>(po + 4) = t1;
                        }
                    }
                }
            }
            first = false;
            bb += CAP;
            __syncthreads();
        } while (bb < end);
    }
}

extern "C" void kernel_launch(void* const* d_in, const int* in_sizes, int n_in,
                              void* d_out, int out_size, void* d_ws, size_t ws_size,
                              hipStream_t stream) {
    const float* x = (const float*)d_in[0];
    const int* A_ind = (const int*)d_in[1];
    const float* A_val = (const float*)d_in[2];
    float* out = (float*)d_out;

    const int nnz = in_sizes[2];
    const int n = out_size / F;              // 100000
    const int nbk = (n + RPB - 1) / RPB;     // 1563 buckets
    const int* rows = A_ind;
    const int* cols = A_ind + nnz;

    const long long xtotal = (long long)n * F;

    const size_t need = (size_t)nnz * 8              // pair
                      + (size_t)xtotal * 2           // x bf16
                      + (size_t)(3 * nbk + 1) * 4 + 128;

    if (nbk > MAXNB || (xtotal % 8) != 0 || ws_size < need) {
        hipMemsetAsync(d_out, 0, (size_t)out_size * sizeof(float), stream);
        const long long total = (long long)nnz * 32;
        spmm_coo_atomic<<<(int)((total + 255) / 256), 256, 0, stream>>>(
            rows, cols, A_val, x, out, nnz, n);
        return;
    }

    char* w = (char*)d_ws;
    int2* pair = (int2*)w;            w += (size_t)nnz * 8;
    unsigned short* xb = (unsigned short*)w;  w += (size_t)xtotal * 2;
    int* cnt = (int*)w;               w += (size_t)nbk * 4;
    int* off = (int*)w;               w += (size_t)(nbk + 1) * 4;
    int* gcur = (int*)w;

    const int nchunks = (nnz + CHUNK - 1) / CHUNK;
    const int cvtb = (int)((xtotal / 8 + 255) / 256);

    hipMemsetAsync(cnt, 0, (size_t)nbk * 4, stream);
    k_cvt_histo<<<cvtb + nchunks, 256, 0, stream>>>(x, xb, xtotal, rows, cnt,
                                                    nnz, nbk, n, cvtb);
    k_bucket_scan<<<1, 256, 0, stream>>>(cnt, off, gcur, nbk);
    k_rank_scatter<<<nchunks, 512, 0, stream>>>(rows, cols, A_val, gcur, pair,
                                                nnz, nbk, n);
    // Writes every output row exactly once (zeros for empty rows) -> no out memset.
    const int pgrid = (nbk < PERSIST) ? nbk : PERSIST;
    k_sort_spmm<<<pgrid, SPMM_T, 0, stream>>>(off, pair, xb, out, n, nbk);
}